// Round 1
// baseline (10986.773 us; speedup 1.0000x reference)
//
#include <hip/hip_runtime.h>
#include <hip/hip_bf16.h>
#include <math.h>
#include <stdint.h>

// ---------------------------------------------------------------------------
// MaskedContextSelector, round 1: correctness-anchor f32 pipeline.
//   K1 proj_gemm : Q = hs@Wq^T + bq ; K = hs@Wk^T + bk       (f32 128x128x8)
//   K2 attn_fused: per 4 query rows: per-head online softmax stats (pass 1),
//                  attn_w = mean_h softmax_h, EL = exp((attn_w + gumbel)/TAU),
//                  row sums L (pass 2). Causal (s < causal_lengths[t]).
//   K3 out_gemm  : out = (EL @ hs) / L, causal-bounded k-loop.
// WS layout (floats): Q[4096*1024] | K[4096*1024] | EL[4096*2048] | L[4096]
//   total ~67.1 MB.
// ---------------------------------------------------------------------------

#define B_   2
#define T_   2048
#define E_   1024
#define NH_  16
#define M_   (B_ * T_)
#define SCALE_ 0.125f          // 1/sqrt(64)
#define NEGM_  -1e30f          // finite -inf so exp(m-m)=1 with z=0 stays 0 (no NaN)

// ------------------------- K1: dual projection GEMM -------------------------
// C[m,n] = sum_e A[m,e]*W[n,e] + bias[n].  blockIdx.z: 0 -> Q, 1 -> K.
__global__ __launch_bounds__(256) void proj_gemm(
    const float* __restrict__ A,
    const float* __restrict__ Wq, const float* __restrict__ bq,
    const float* __restrict__ Wk, const float* __restrict__ bk,
    float* __restrict__ Qws, float* __restrict__ Kws)
{
  const int n0 = blockIdx.x * 128;
  const int m0 = blockIdx.y * 128;
  const float* __restrict__ Wm  = blockIdx.z ? Wk : Wq;
  const float* __restrict__ bia = blockIdx.z ? bk : bq;
  float* __restrict__ C = blockIdx.z ? Kws : Qws;

  __shared__ float As[8][128];   // k-major
  __shared__ float Bs[8][128];

  const int tid = threadIdx.x;
  const int tm = (tid >> 4) * 8;
  const int tn = (tid & 15) * 8;
  const int lr = tid >> 1;         // staging row 0..127
  const int lc = (tid & 1) * 4;    // staging col 0 or 4

  float acc[8][8];
  #pragma unroll
  for (int i = 0; i < 8; ++i)
    #pragma unroll
    for (int j = 0; j < 8; ++j) acc[i][j] = 0.f;

  for (int kt = 0; kt < E_; kt += 8) {
    const float4 av = *(const float4*)(A  + (size_t)(m0 + lr) * E_ + kt + lc);
    const float4 bv = *(const float4*)(Wm + (size_t)(n0 + lr) * E_ + kt + lc);
    __syncthreads();
    As[lc + 0][lr] = av.x; As[lc + 1][lr] = av.y;
    As[lc + 2][lr] = av.z; As[lc + 3][lr] = av.w;
    Bs[lc + 0][lr] = bv.x; Bs[lc + 1][lr] = bv.y;
    Bs[lc + 2][lr] = bv.z; Bs[lc + 3][lr] = bv.w;
    __syncthreads();
    #pragma unroll
    for (int kk = 0; kk < 8; ++kk) {
      float af[8], bf[8];
      *(float4*)&af[0] = *(const float4*)&As[kk][tm];
      *(float4*)&af[4] = *(const float4*)&As[kk][tm + 4];
      *(float4*)&bf[0] = *(const float4*)&Bs[kk][tn];
      *(float4*)&bf[4] = *(const float4*)&Bs[kk][tn + 4];
      #pragma unroll
      for (int i = 0; i < 8; ++i)
        #pragma unroll
        for (int j = 0; j < 8; ++j)
          acc[i][j] = fmaf(af[i], bf[j], acc[i][j]);
    }
  }

  const float4 b0 = *(const float4*)(bia + n0 + tn);
  const float4 b1 = *(const float4*)(bia + n0 + tn + 4);
  #pragma unroll
  for (int i = 0; i < 8; ++i) {
    const float4 o0 = make_float4(acc[i][0] + b0.x, acc[i][1] + b0.y,
                                  acc[i][2] + b0.z, acc[i][3] + b0.w);
    const float4 o1 = make_float4(acc[i][4] + b1.x, acc[i][5] + b1.y,
                                  acc[i][6] + b1.z, acc[i][7] + b1.w);
    float* dst = C + (size_t)(m0 + tm + i) * E_ + n0 + tn;
    *(float4*)dst = o0;
    *(float4*)(dst + 4) = o1;
  }
}

// ------------------------- K2: fused attention chain -------------------------
// Each block: batch b, 4 consecutive query rows. 4 waves; wave = head-group hg
// (heads 4hg..4hg+3, e-slice [256hg, 256hg+256)). Per s (one per lane):
// sc[t][hl] = q[t] . k[s] over that head's 64 dims.
__device__ __forceinline__ void score_slice(const float4* __restrict__ q4,
                                            const float4* __restrict__ kp,
                                            int hg, float sc[4][4])
{
  #pragma unroll
  for (int hl = 0; hl < 4; ++hl) {
    #pragma unroll
    for (int i2 = 0; i2 < 16; ++i2) {
      const float4 kv = kp[hl * 16 + i2];
      #pragma unroll
      for (int t = 0; t < 4; ++t) {
        const float4 qv = q4[t * 256 + hg * 64 + hl * 16 + i2];  // LDS broadcast
        sc[t][hl] = fmaf(qv.x, kv.x, fmaf(qv.y, kv.y,
                     fmaf(qv.z, kv.z, fmaf(qv.w, kv.w, sc[t][hl]))));
      }
    }
  }
}

__global__ __launch_bounds__(256) void attn_fused(
    const float* __restrict__ Qws, const float* __restrict__ Kws,
    const float* __restrict__ gum, const int* __restrict__ clen,
    float* __restrict__ ELws, float* __restrict__ Lws)
{
  const int blk  = blockIdx.x;
  const int b    = blk / (T_ / 4);
  const int t0   = (T_ / 4 - 1 - (blk % (T_ / 4))) * 4;  // long rows first (causal balance)
  const int tid  = threadIdx.x;
  const int hg   = tid >> 6;     // wave id == head group == owned row in EL phase
  const int lane = tid & 63;

  __shared__ float q_s[4 * E_];            // 16 KB
  __shared__ float mz_s[4][NH_][2];        // per (t,h): {m, 1/z}
  __shared__ float attn_s[4][4][64];       // [hg][t][lane] partial attn_w
  __shared__ int   len_s[4];

  {
    const float4* src = (const float4*)(Qws + (size_t)(b * T_ + t0) * E_);
    float4* dst = (float4*)q_s;
    #pragma unroll
    for (int j = 0; j < 4; ++j) dst[tid + j * 256] = src[tid + j * 256];
  }
  if (tid < 4) {
    int l = clen[t0 + tid];
    len_s[tid] = l < 0 ? 0 : (l > T_ ? T_ : l);
  }
  __syncthreads();

  const int len0 = len_s[0], len1 = len_s[1], len2 = len_s[2], len3 = len_s[3];
  const int len_max = max(max(len0, len1), max(len2, len3));
  const int mylen = len_s[hg];

  const float4* q4 = (const float4*)q_s;
  const float*  kb = Kws + (size_t)b * T_ * E_;

  // ---------------- pass 1: per-head online max/sumexp ----------------
  float m[4][4], z[4][4];
  #pragma unroll
  for (int t = 0; t < 4; ++t)
    #pragma unroll
    for (int hl = 0; hl < 4; ++hl) { m[t][hl] = NEGM_; z[t][hl] = 0.f; }

  for (int s = lane; s < len_max; s += 64) {
    const float4* kp = (const float4*)(kb + (size_t)s * E_ + hg * 256);
    float sc[4][4] = {};
    score_slice(q4, kp, hg, sc);
    #pragma unroll
    for (int t = 0; t < 4; ++t) {
      const int lt = (t == 0) ? len0 : (t == 1) ? len1 : (t == 2) ? len2 : len3;
      if (s < lt) {
        #pragma unroll
        for (int hl = 0; hl < 4; ++hl) {
          const float v  = sc[t][hl] * SCALE_;
          const float mn = fmaxf(m[t][hl], v);
          z[t][hl] = z[t][hl] * __expf(m[t][hl] - mn) + __expf(v - mn);
          m[t][hl] = mn;
        }
      }
    }
  }

  // wave-reduce (m,z) per (t, head)
  #pragma unroll
  for (int t = 0; t < 4; ++t) {
    #pragma unroll
    for (int hl = 0; hl < 4; ++hl) {
      float mm = m[t][hl], zz = z[t][hl];
      #pragma unroll
      for (int off = 32; off; off >>= 1) {
        const float mo = __shfl_xor(mm, off);
        const float zo = __shfl_xor(zz, off);
        const float mn = fmaxf(mm, mo);
        zz = zz * __expf(mm - mn) + zo * __expf(mo - mn);
        mm = mn;
      }
      if (lane == 0) {
        mz_s[t][hg * 4 + hl][0] = mm;
        mz_s[t][hg * 4 + hl][1] = (zz > 0.f) ? 1.f / zz : 0.f;
      }
    }
  }
  __syncthreads();

  float rm[4][4], rz[4][4];
  #pragma unroll
  for (int t = 0; t < 4; ++t)
    #pragma unroll
    for (int hl = 0; hl < 4; ++hl) {
      rm[t][hl] = mz_s[t][hg * 4 + hl][0];
      rz[t][hl] = mz_s[t][hg * 4 + hl][1];
    }

  // ---------------- pass 2: attn_w -> gumbel logits -> EL, row sums ----------------
  float lsum = 0.f;
  const size_t myrow = (size_t)(b * T_ + t0 + hg);

  for (int c0 = 0; c0 < len_max; c0 += 64) {
    const int s = c0 + lane;     // s < T_ guaranteed (T_ multiple of 64)
    {
      float sc[4][4] = {};
      score_slice(q4, (const float4*)(kb + (size_t)s * E_ + hg * 256), hg, sc);
      #pragma unroll
      for (int t = 0; t < 4; ++t) {
        const int lt = (t == 0) ? len0 : (t == 1) ? len1 : (t == 2) ? len2 : len3;
        float a = 0.f;
        if (s < lt) {
          #pragma unroll
          for (int hl = 0; hl < 4; ++hl)
            a += __expf(sc[t][hl] * SCALE_ - rm[t][hl]) * rz[t][hl];
        }
        attn_s[hg][t][lane] = a;
      }
    }
    __syncthreads();
    {
      float el = 0.f;
      if (s < mylen) {
        // mean over 16 heads (4 head-group partials); softmax mean is in [0,1]
        // so the reference's clip(+-40) is a no-op.
        const float aw = (attn_s[0][hg][lane] + attn_s[1][hg][lane] +
                          attn_s[2][hg][lane] + attn_s[3][hg][lane]) * (1.f / NH_);
        const float u = gum[myrow * (size_t)T_ + s];
        const float g = -logf(-logf(u));
        // logits in [-1.31, 7.41] -> exp safe without max subtraction
        el = expf((aw + g) * 0.5f);   // /TAU, TAU=2
      }
      ELws[myrow * (size_t)T_ + s] = el;   // zero for masked s
      lsum += el;
    }
    __syncthreads();
  }

  // zero tail columns [round64(len_max), T)
  const int zstart = (len_max + 63) & ~63;
  for (int t = 0; t < 4; ++t) {
    const size_t row = (size_t)(b * T_ + t0 + t);
    for (int s = zstart + tid; s < T_; s += 256)
      ELws[row * T_ + s] = 0.f;
  }

  #pragma unroll
  for (int off = 32; off; off >>= 1) lsum += __shfl_xor(lsum, off);
  if (lane == 0) Lws[myrow] = (mylen > 0) ? lsum : 1.f;  // len==0 row -> out 0
}

// ------------------------- K3: output GEMM + normalize -------------------------
// out[b,t,:] = (sum_s EL[b,t,s] * hs[b,s,:]) / L[b,t]; k-loop bounded by block smax.
__global__ __launch_bounds__(256) void out_gemm(
    const float* __restrict__ ELws, const float* __restrict__ hs,
    const float* __restrict__ Lws, const int* __restrict__ clen,
    float* __restrict__ outp)
{
  const int n0 = blockIdx.x * 128;
  const int t0 = ((int)gridDim.y - 1 - (int)blockIdx.y) * 128;  // long tiles first
  const int b  = blockIdx.z;
  const int tid = threadIdx.x;

  __shared__ float As[8][128];
  __shared__ float Bs[8][128];
  __shared__ int smax_sh;

  if (tid == 0) smax_sh = 0;
  __syncthreads();
  if (tid < 128) {
    int l = clen[t0 + tid];
    l = l < 0 ? 0 : (l > T_ ? T_ : l);
    atomicMax(&smax_sh, l);
  }
  __syncthreads();
  const int smax = smax_sh;

  const int tm = (tid >> 4) * 8, tn = (tid & 15) * 8;
  const int lr = tid >> 1,       lc = (tid & 1) * 4;   // EL staging
  const int br = tid >> 5,       bc = (tid & 31) * 4;  // hs staging

  float acc[8][8];
  #pragma unroll
  for (int i = 0; i < 8; ++i)
    #pragma unroll
    for (int j = 0; j < 8; ++j) acc[i][j] = 0.f;

  for (int s0 = 0; s0 < smax; s0 += 8) {   // cols stay < T_ (T_ % 8 == 0; EL tail zeroed)
    const float4 av = *(const float4*)(ELws + (size_t)(b * T_ + t0 + lr) * T_ + s0 + lc);
    const float4 bv = *(const float4*)(hs  + (size_t)(b * T_ + s0 + br) * E_ + n0 + bc);
    __syncthreads();
    As[lc + 0][lr] = av.x; As[lc + 1][lr] = av.y;
    As[lc + 2][lr] = av.z; As[lc + 3][lr] = av.w;
    *(float4*)&Bs[br][bc] = bv;
    __syncthreads();
    #pragma unroll
    for (int kk = 0; kk < 8; ++kk) {
      float af[8], bf[8];
      *(float4*)&af[0] = *(const float4*)&As[kk][tm];
      *(float4*)&af[4] = *(const float4*)&As[kk][tm + 4];
      *(float4*)&bf[0] = *(const float4*)&Bs[kk][tn];
      *(float4*)&bf[4] = *(const float4*)&Bs[kk][tn + 4];
      #pragma unroll
      for (int i = 0; i < 8; ++i)
        #pragma unroll
        for (int j = 0; j < 8; ++j)
          acc[i][j] = fmaf(af[i], bf[j], acc[i][j]);
    }
  }

  #pragma unroll
  for (int i = 0; i < 8; ++i) {
    const float li = 1.f / Lws[b * T_ + t0 + tm + i];
    const float4 o0 = make_float4(acc[i][0] * li, acc[i][1] * li,
                                  acc[i][2] * li, acc[i][3] * li);
    const float4 o1 = make_float4(acc[i][4] * li, acc[i][5] * li,
                                  acc[i][6] * li, acc[i][7] * li);
    float* dst = outp + (size_t)(b * T_ + t0 + tm + i) * E_ + n0 + tn;
    *(float4*)dst = o0;
    *(float4*)(dst + 4) = o1;
  }
}

// ------------------------------- launcher -------------------------------
extern "C" void kernel_launch(void* const* d_in, const int* in_sizes, int n_in,
                              void* d_out, int out_size, void* d_ws, size_t ws_size,
                              hipStream_t stream) {
  const float* hs  = (const float*)d_in[0];
  const float* Wq  = (const float*)d_in[1];
  const float* bq  = (const float*)d_in[2];
  const float* Wk  = (const float*)d_in[3];
  const float* bk  = (const float*)d_in[4];
  const float* gum = (const float*)d_in[5];
  const int*   cl  = (const int*)d_in[6];
  float* out = (float*)d_out;

  // workspace carving (floats). Needs ~67.1 MB.
  float* w    = (float*)d_ws;
  float* Qws  = w;
  float* Kws  = w + (size_t)M_ * E_;
  float* ELws = w + 2 * (size_t)M_ * E_;
  float* Lws  = ELws + (size_t)M_ * T_;
  (void)ws_size; (void)in_sizes; (void)n_in; (void)out_size;

  proj_gemm<<<dim3(E_ / 128, M_ / 128, 2), 256, 0, stream>>>(
      hs, Wq, bq, Wk, bk, Qws, Kws);
  attn_fused<<<dim3(M_ / 4), 256, 0, stream>>>(
      Qws, Kws, gum, cl, ELws, Lws);
  out_gemm<<<dim3(E_ / 128, T_ / 128, B_), 256, 0, stream>>>(
      ELws, hs, Lws, cl, out);
}

// Round 2
// 938.220 us; speedup vs baseline: 11.7102x; 11.7102x over previous
//
#include <hip/hip_runtime.h>
#include <hip/hip_bf16.h>
#include <math.h>
#include <stdint.h>

// ---------------------------------------------------------------------------
// MaskedContextSelector, round 2: MFMA attention chain.
//   K1 proj_gemm : Q,K = hs@W^T + b  (f32 compute, bf16 output)
//   K2a zsum     : rz[b,h,t] = 1 / sum_{s<len(t)} exp(score*scale)   (MFMA)
//   K2b elgen    : EL = exp((mean_h softmax_h + gumbel)/TAU), L row sums (MFMA)
//   K3 out_gemm  : out = (EL @ hs) / L   (f32)
// WS: Qb bf16[4096*1024] | Kb bf16[4096*1024] | rz f32[2*16*2048]
//     | EL f32[4096*2048] | L f32[4096]   ~50.3 MB
// No max-subtraction in softmax: scores ~N(0,1), max ~6 over 1.3e8 samples,
// exp safe in f32; identical math to reference otherwise.
// ---------------------------------------------------------------------------

#define B_   2
#define T_   2048
#define E_   1024
#define NH_  16
#define DH_  64
#define M_   (B_ * T_)
#define SCALE_ 0.125f          // 1/sqrt(64)

typedef __attribute__((ext_vector_type(8))) short bf16x8;   // 8 bf16 = 4 VGPR
typedef __attribute__((ext_vector_type(4))) float f32x4;

__device__ __forceinline__ short f2bf(float x) {
  __hip_bfloat16 h = __float2bfloat16(x);
  return *reinterpret_cast<short*>(&h);
}

// ------------------------- K1: dual projection GEMM (f32 -> bf16) ----------
__global__ __launch_bounds__(256) void proj_gemm(
    const float* __restrict__ A,
    const float* __restrict__ Wq, const float* __restrict__ bq,
    const float* __restrict__ Wk, const float* __restrict__ bk,
    short* __restrict__ Qb, short* __restrict__ Kb)
{
  const int n0 = blockIdx.x * 128;
  const int m0 = blockIdx.y * 128;
  const float* __restrict__ Wm  = blockIdx.z ? Wk : Wq;
  const float* __restrict__ bia = blockIdx.z ? bk : bq;
  short* __restrict__ C = blockIdx.z ? Kb : Qb;

  __shared__ float As[8][128];
  __shared__ float Bs[8][128];

  const int tid = threadIdx.x;
  const int tm = (tid >> 4) * 8;
  const int tn = (tid & 15) * 8;
  const int lr = tid >> 1;
  const int lc = (tid & 1) * 4;

  float acc[8][8];
  #pragma unroll
  for (int i = 0; i < 8; ++i)
    #pragma unroll
    for (int j = 0; j < 8; ++j) acc[i][j] = 0.f;

  for (int kt = 0; kt < E_; kt += 8) {
    const float4 av = *(const float4*)(A  + (size_t)(m0 + lr) * E_ + kt + lc);
    const float4 bv = *(const float4*)(Wm + (size_t)(n0 + lr) * E_ + kt + lc);
    __syncthreads();
    As[lc + 0][lr] = av.x; As[lc + 1][lr] = av.y;
    As[lc + 2][lr] = av.z; As[lc + 3][lr] = av.w;
    Bs[lc + 0][lr] = bv.x; Bs[lc + 1][lr] = bv.y;
    Bs[lc + 2][lr] = bv.z; Bs[lc + 3][lr] = bv.w;
    __syncthreads();
    #pragma unroll
    for (int kk = 0; kk < 8; ++kk) {
      float af[8], bf[8];
      *(float4*)&af[0] = *(const float4*)&As[kk][tm];
      *(float4*)&af[4] = *(const float4*)&As[kk][tm + 4];
      *(float4*)&bf[0] = *(const float4*)&Bs[kk][tn];
      *(float4*)&bf[4] = *(const float4*)&Bs[kk][tn + 4];
      #pragma unroll
      for (int i = 0; i < 8; ++i)
        #pragma unroll
        for (int j = 0; j < 8; ++j)
          acc[i][j] = fmaf(af[i], bf[j], acc[i][j]);
    }
  }

  float bv[8];
  *(float4*)&bv[0] = *(const float4*)(bia + n0 + tn);
  *(float4*)&bv[4] = *(const float4*)(bia + n0 + tn + 4);
  #pragma unroll
  for (int i = 0; i < 8; ++i) {
    bf16x8 o;
    #pragma unroll
    for (int j = 0; j < 8; ++j) o[j] = f2bf(acc[i][j] + bv[j]);
    *(bf16x8*)(C + (size_t)(m0 + tm + i) * E_ + n0 + tn) = o;
  }
}

// ------------------------- K2a: per-head softmax denominators --------------
// grid (T/64, NH, B), 256 thr = 4 waves; wave w owns q-rows t0+16w..+15.
// Fragments (mfma_f32_16x16x32_bf16): A row=lane&15, k=(lane>>4)*8+j;
// B col=lane&15, same k; C/D col=lane&15, row=(lane>>4)*4+reg.
__global__ __launch_bounds__(256) void zsum_kernel(
    const short* __restrict__ Qb, const short* __restrict__ Kb,
    const int* __restrict__ clen, float* __restrict__ rzinv)
{
  const int b = blockIdx.z, h = blockIdx.y;
  const int t0 = ((int)gridDim.x - 1 - (int)blockIdx.x) * 64;  // long rows first
  const int w = threadIdx.x >> 6, l = threadIdx.x & 63;
  const int lg = l >> 4, li = l & 15;
  const int tw = t0 + w * 16;

  const short* qrow = Qb + (size_t)(b * T_ + tw + li) * E_ + h * DH_ + lg * 8;
  const bf16x8 af0 = *(const bf16x8*)(qrow);
  const bf16x8 af1 = *(const bf16x8*)(qrow + 32);

  int lenc[4];
  #pragma unroll
  for (int r = 0; r < 4; ++r) {
    int L = clen[tw + lg * 4 + r];
    lenc[r] = L < 0 ? 0 : (L > T_ ? T_ : L);
  }
  int wmax = max(max(lenc[0], lenc[1]), max(lenc[2], lenc[3]));
  #pragma unroll
  for (int off = 32; off; off >>= 1) wmax = max(wmax, __shfl_xor(wmax, off));

  float zacc[4] = {0.f, 0.f, 0.f, 0.f};
  const short* kbase = Kb + (size_t)b * T_ * E_ + h * DH_ + lg * 8;

  for (int s0 = 0; s0 < wmax; s0 += 64) {
    f32x4 sc[4];
    #pragma unroll
    for (int n = 0; n < 4; ++n) {
      const short* krow = kbase + (size_t)(s0 + n * 16 + li) * E_;
      const bf16x8 bf0 = *(const bf16x8*)(krow);
      const bf16x8 bf1 = *(const bf16x8*)(krow + 32);
      f32x4 z4 = {0.f, 0.f, 0.f, 0.f};
      z4 = __builtin_amdgcn_mfma_f32_16x16x32_bf16(af0, bf0, z4, 0, 0, 0);
      z4 = __builtin_amdgcn_mfma_f32_16x16x32_bf16(af1, bf1, z4, 0, 0, 0);
      sc[n] = z4;
    }
    #pragma unroll
    for (int n = 0; n < 4; ++n) {
      const int s = s0 + n * 16 + li;
      #pragma unroll
      for (int r = 0; r < 4; ++r)
        if (s < lenc[r]) zacc[r] += __expf(sc[n][r] * SCALE_);
    }
  }

  #pragma unroll
  for (int r = 0; r < 4; ++r) {
    float z = zacc[r];
    #pragma unroll
    for (int off = 1; off < 16; off <<= 1) z += __shfl_xor(z, off);
    if (li == 0) {
      const int t = tw + lg * 4 + r;
      rzinv[(size_t)(b * NH_ + h) * T_ + t] =
          (lenc[r] > 0 && z > 0.f) ? 1.f / z : 0.f;
    }
  }
}

// ------------------------- K2b: attn_w -> gumbel -> EL, L ------------------
// grid (T/16, B), 256 thr = 4 waves; wave w owns heads 4w..4w+3; block owns
// q-rows t0..t0+15 fully (cross-head combine in LDS).
__global__ __launch_bounds__(256) void elgen_kernel(
    const short* __restrict__ Qb, const short* __restrict__ Kb,
    const float* __restrict__ rzinv, const float* __restrict__ gum,
    const int* __restrict__ clen,
    float* __restrict__ EL, float* __restrict__ Lws)
{
  const int b = blockIdx.y;
  const int t0 = ((int)gridDim.x - 1 - (int)blockIdx.x) * 16;
  const int tid = threadIdx.x;
  const int w = tid >> 6, l = tid & 63;
  const int lg = l >> 4, li = l & 15;

  __shared__ float awbuf[4][16][68];   // [wave][row][col], 68-pad: bank spread
  __shared__ int len_s[16];
  __shared__ int lmax_s;

  if (tid < 16) {
    int L = clen[t0 + tid];
    len_s[tid] = L < 0 ? 0 : (L > T_ ? T_ : L);
  }
  __syncthreads();
  if (tid == 0) {
    int m = 0;
    for (int i = 0; i < 16; ++i) m = max(m, len_s[i]);
    lmax_s = m;
  }

  bf16x8 af[4][2];
  const short* qrow = Qb + (size_t)(b * T_ + t0 + li) * E_ + lg * 8;
  #pragma unroll
  for (int hl = 0; hl < 4; ++hl) {
    af[hl][0] = *(const bf16x8*)(qrow + (w * 4 + hl) * DH_);
    af[hl][1] = *(const bf16x8*)(qrow + (w * 4 + hl) * DH_ + 32);
  }
  float rz[4][4];
  #pragma unroll
  for (int hl = 0; hl < 4; ++hl)
    #pragma unroll
    for (int r = 0; r < 4; ++r)
      rz[hl][r] = rzinv[(size_t)(b * NH_ + w * 4 + hl) * T_ + t0 + lg * 4 + r];
  __syncthreads();
  const int lmax = lmax_s;

  const int erow = tid >> 4;          // EL-phase row 0..15 (wave w: rows 4w..4w+3)
  const int c0 = (tid & 15) * 4;      // EL-phase 4-col slot
  const int elen = len_s[erow];
  float lacc = 0.f;
  const short* kbase = Kb + (size_t)b * T_ * E_ + lg * 8;

  for (int s0 = 0; s0 < lmax; s0 += 64) {
    float awp[4][4];                  // [n][reg]
    #pragma unroll
    for (int n = 0; n < 4; ++n)
      #pragma unroll
      for (int r = 0; r < 4; ++r) awp[n][r] = 0.f;

    #pragma unroll
    for (int hl = 0; hl < 4; ++hl) {
      f32x4 sc[4];
      #pragma unroll
      for (int n = 0; n < 4; ++n) {
        const short* krow = kbase + (size_t)(s0 + n * 16 + li) * E_ + (w * 4 + hl) * DH_;
        const bf16x8 bf0 = *(const bf16x8*)(krow);
        const bf16x8 bf1 = *(const bf16x8*)(krow + 32);
        f32x4 z4 = {0.f, 0.f, 0.f, 0.f};
        z4 = __builtin_amdgcn_mfma_f32_16x16x32_bf16(af[hl][0], bf0, z4, 0, 0, 0);
        z4 = __builtin_amdgcn_mfma_f32_16x16x32_bf16(af[hl][1], bf1, z4, 0, 0, 0);
        sc[n] = z4;
      }
      #pragma unroll
      for (int n = 0; n < 4; ++n)
        #pragma unroll
        for (int r = 0; r < 4; ++r)
          awp[n][r] += __expf(sc[n][r] * SCALE_) * rz[hl][r];
    }
    #pragma unroll
    for (int n = 0; n < 4; ++n)
      #pragma unroll
      for (int r = 0; r < 4; ++r)
        awbuf[w][lg * 4 + r][n * 16 + li] = awp[n][r];
    __syncthreads();

    // EL phase: combine 4 wave-partials, gumbel, store EL, accumulate L.
    float el[4];
    #pragma unroll
    for (int j = 0; j < 4; ++j) {
      const float aw = awbuf[0][erow][c0 + j] + awbuf[1][erow][c0 + j] +
                       awbuf[2][erow][c0 + j] + awbuf[3][erow][c0 + j];
      const int s = s0 + c0 + j;
      float e = 0.f;
      if (s < elen) {
        const float u = gum[(size_t)(b * T_ + t0 + erow) * T_ + s];
        const float g = -__logf(-__logf(u));
        e = expf((aw * (1.f / NH_) + g) * 0.5f);   // /TAU, TAU=2
      }
      el[j] = e;
      lacc += e;
    }
    *(float4*)(EL + (size_t)(b * T_ + t0 + erow) * T_ + s0 + c0) =
        make_float4(el[0], el[1], el[2], el[3]);
    __syncthreads();
  }

  // zero tail columns [round64(lmax), T)
  const int zstart = (lmax + 63) & ~63;
  for (int r = 0; r < 16; ++r) {
    float* dst = EL + (size_t)(b * T_ + t0 + r) * T_;
    for (int c = zstart + tid * 4; c < T_; c += 1024)
      *(float4*)(dst + c) = make_float4(0.f, 0.f, 0.f, 0.f);
  }

  #pragma unroll
  for (int off = 1; off < 16; off <<= 1) lacc += __shfl_xor(lacc, off);
  if (li == 0)
    Lws[(size_t)(b * T_) + t0 + erow] = (elen > 0) ? lacc : 1.f;
}

// ------------------------- K3: output GEMM + normalize ---------------------
__global__ __launch_bounds__(256) void out_gemm(
    const float* __restrict__ ELws, const float* __restrict__ hs,
    const float* __restrict__ Lws, const int* __restrict__ clen,
    float* __restrict__ outp)
{
  const int n0 = blockIdx.x * 128;
  const int t0 = ((int)gridDim.y - 1 - (int)blockIdx.y) * 128;
  const int b  = blockIdx.z;
  const int tid = threadIdx.x;

  __shared__ float As[8][128];
  __shared__ float Bs[8][128];
  __shared__ int smax_sh;

  if (tid == 0) smax_sh = 0;
  __syncthreads();
  if (tid < 128) {
    int L = clen[t0 + tid];
    L = L < 0 ? 0 : (L > T_ ? T_ : L);
    atomicMax(&smax_sh, L);
  }
  __syncthreads();
  const int smax = smax_sh;

  const int tm = (tid >> 4) * 8, tn = (tid & 15) * 8;
  const int lr = tid >> 1,       lc = (tid & 1) * 4;
  const int br = tid >> 5,       bc = (tid & 31) * 4;

  float acc[8][8];
  #pragma unroll
  for (int i = 0; i < 8; ++i)
    #pragma unroll
    for (int j = 0; j < 8; ++j) acc[i][j] = 0.f;

  for (int s0 = 0; s0 < smax; s0 += 8) {
    const float4 av = *(const float4*)(ELws + (size_t)(b * T_ + t0 + lr) * T_ + s0 + lc);
    const float4 bv = *(const float4*)(hs  + (size_t)(b * T_ + s0 + br) * E_ + n0 + bc);
    __syncthreads();
    As[lc + 0][lr] = av.x; As[lc + 1][lr] = av.y;
    As[lc + 2][lr] = av.z; As[lc + 3][lr] = av.w;
    *(float4*)&Bs[br][bc] = bv;
    __syncthreads();
    #pragma unroll
    for (int kk = 0; kk < 8; ++kk) {
      float af[8], bf[8];
      *(float4*)&af[0] = *(const float4*)&As[kk][tm];
      *(float4*)&af[4] = *(const float4*)&As[kk][tm + 4];
      *(float4*)&bf[0] = *(const float4*)&Bs[kk][tn];
      *(float4*)&bf[4] = *(const float4*)&Bs[kk][tn + 4];
      #pragma unroll
      for (int i = 0; i < 8; ++i)
        #pragma unroll
        for (int j = 0; j < 8; ++j)
          acc[i][j] = fmaf(af[i], bf[j], acc[i][j]);
    }
  }

  #pragma unroll
  for (int i = 0; i < 8; ++i) {
    const float li = 1.f / Lws[b * T_ + t0 + tm + i];
    const float4 o0 = make_float4(acc[i][0] * li, acc[i][1] * li,
                                  acc[i][2] * li, acc[i][3] * li);
    const float4 o1 = make_float4(acc[i][4] * li, acc[i][5] * li,
                                  acc[i][6] * li, acc[i][7] * li);
    float* dst = outp + (size_t)(b * T_ + t0 + tm + i) * E_ + n0 + tn;
    *(float4*)dst = o0;
    *(float4*)(dst + 4) = o1;
  }
}

// ------------------------------- launcher ----------------------------------
extern "C" void kernel_launch(void* const* d_in, const int* in_sizes, int n_in,
                              void* d_out, int out_size, void* d_ws, size_t ws_size,
                              hipStream_t stream) {
  const float* hs  = (const float*)d_in[0];
  const float* Wq  = (const float*)d_in[1];
  const float* bq  = (const float*)d_in[2];
  const float* Wk  = (const float*)d_in[3];
  const float* bk  = (const float*)d_in[4];
  const float* gum = (const float*)d_in[5];
  const int*   cl  = (const int*)d_in[6];
  float* out = (float*)d_out;

  short* Qb = (short*)d_ws;
  short* Kb = Qb + (size_t)M_ * E_;
  float* rz = (float*)(Kb + (size_t)M_ * E_);
  float* EL = rz + (size_t)B_ * NH_ * T_;
  float* Lw = EL + (size_t)M_ * T_;
  (void)ws_size; (void)in_sizes; (void)n_in; (void)out_size;

  proj_gemm<<<dim3(E_ / 128, M_ / 128, 2), 256, 0, stream>>>(
      hs, Wq, bq, Wk, bk, Qb, Kb);
  zsum_kernel<<<dim3(T_ / 64, NH_, B_), 256, 0, stream>>>(
      Qb, Kb, cl, rz);
  elgen_kernel<<<dim3(T_ / 16, B_), 256, 0, stream>>>(
      Qb, Kb, rz, gum, cl, EL, Lw);
  out_gemm<<<dim3(E_ / 128, T_ / 128, B_), 256, 0, stream>>>(
      EL, hs, Lw, cl, out);
}

// Round 3
// 450.641 us; speedup vs baseline: 24.3803x; 2.0820x over previous
//
#include <hip/hip_runtime.h>
#include <hip/hip_bf16.h>
#include <math.h>
#include <stdint.h>

// ---------------------------------------------------------------------------
// MaskedContextSelector, round 3: all-MFMA pipeline.
//   K0a prep_hs  : hs_hi = bf16(hs); hsT_hi/lo = transposed bf16 hi/lo split
//   K0b cast_w   : Wq,Wk -> bf16
//   K1  proj_mfma: Q,K = bf16MFMA(hs_hi @ W^T) + bias -> bf16
//   K2a zsum     : per-head softmax denominators (MFMA)
//   K2b elgen    : EL = exp((mean_h softmax_h + gumbel)/TAU) -> bf16 hi/lo,
//                  L row sums via atomicAdd; s-strip-split grid for occupancy
//   K3  out_mfma : out = (ELh@Hh + ELh@Hl + ELl@Hh)/L   (split-compensated)
// ---------------------------------------------------------------------------

#define B_   2
#define T_   2048
#define E_   1024
#define NH_  16
#define DH_  64
#define M_   (B_ * T_)
#define SCALE_ 0.125f
#define NSTRIP_ 4

typedef __attribute__((ext_vector_type(8))) short bf16x8;
typedef __attribute__((ext_vector_type(4))) float f32x4;

__device__ __forceinline__ short f2bf(float x) {
  __hip_bfloat16 h = __float2bfloat16(x);
  return *reinterpret_cast<short*>(&h);
}
__device__ __forceinline__ float bf2f(short x) {
  __hip_bfloat16 h = *reinterpret_cast<__hip_bfloat16*>(&x);
  return __bfloat162float(h);
}

// ------------------- K0a: cast + transpose hidden states -------------------
// grid (T/64, E/64, B). Writes hs_hi[b*T+s][e], hsT_hi/lo[(b*E+e)][s].
__global__ __launch_bounds__(256) void prep_hs(
    const float* __restrict__ hs, short* __restrict__ hs_hi,
    short* __restrict__ hsT_hi, short* __restrict__ hsT_lo)
{
  const int b = blockIdx.z;
  const int s0 = blockIdx.x * 64, e0 = blockIdx.y * 64;
  __shared__ float tile[64][65];
  const int tid = threadIdx.x;
  const int r = tid >> 4, c4 = (tid & 15) * 4;

  #pragma unroll
  for (int rr = 0; rr < 64; rr += 16) {
    const float4 v = *(const float4*)(hs + (size_t)(b * T_ + s0 + r + rr) * E_ + e0 + c4);
    ushort4 o;
    o.x = (unsigned short)f2bf(v.x); o.y = (unsigned short)f2bf(v.y);
    o.z = (unsigned short)f2bf(v.z); o.w = (unsigned short)f2bf(v.w);
    *(ushort4*)(hs_hi + (size_t)(b * T_ + s0 + r + rr) * E_ + e0 + c4) = o;
    tile[r + rr][c4 + 0] = v.x; tile[r + rr][c4 + 1] = v.y;
    tile[r + rr][c4 + 2] = v.z; tile[r + rr][c4 + 3] = v.w;
  }
  __syncthreads();
  #pragma unroll
  for (int rr = 0; rr < 64; rr += 16) {
    ushort4 oh, ol;
    #pragma unroll
    for (int j = 0; j < 4; ++j) {
      const float v = tile[c4 + j][r + rr];
      const short hi = f2bf(v);
      const short lo = f2bf(v - bf2f(hi));
      ((unsigned short*)&oh)[j] = (unsigned short)hi;
      ((unsigned short*)&ol)[j] = (unsigned short)lo;
    }
    const size_t dst = (size_t)(b * E_ + e0 + r + rr) * T_ + s0 + c4;
    *(ushort4*)(hsT_hi + dst) = oh;
    *(ushort4*)(hsT_lo + dst) = ol;
  }
}

// ------------------------------ K0b: cast W --------------------------------
__global__ __launch_bounds__(256) void cast_w(
    const float* __restrict__ Wq, const float* __restrict__ Wk,
    short* __restrict__ Wqb, short* __restrict__ Wkb)
{
  const size_t i = ((size_t)blockIdx.x * 256 + threadIdx.x) * 4;
  const float4 q = *(const float4*)(Wq + i);
  const float4 k = *(const float4*)(Wk + i);
  ushort4 oq, ok;
  oq.x = (unsigned short)f2bf(q.x); oq.y = (unsigned short)f2bf(q.y);
  oq.z = (unsigned short)f2bf(q.z); oq.w = (unsigned short)f2bf(q.w);
  ok.x = (unsigned short)f2bf(k.x); ok.y = (unsigned short)f2bf(k.y);
  ok.z = (unsigned short)f2bf(k.z); ok.w = (unsigned short)f2bf(k.w);
  *(ushort4*)(Wqb + i) = oq;
  *(ushort4*)(Wkb + i) = ok;
}

// --------------------------- K1: projection MFMA ---------------------------
// C[m,n] = sum_k hs_hi[m,k]*W[n,k] + bias[n] -> bf16. 128x128 tile, BK=64.
__global__ __launch_bounds__(256) void proj_mfma(
    const short* __restrict__ hsb,
    const short* __restrict__ Wqb, const short* __restrict__ Wkb,
    const float* __restrict__ bq, const float* __restrict__ bk,
    short* __restrict__ Qb, short* __restrict__ Kb)
{
  const int nt = blockIdx.x;                 // 0..15 (0-7 Q, 8-15 K)
  const int m0 = blockIdx.y * 128;
  const bool isK = nt >= 8;
  const short* __restrict__ Wsel = isK ? Wkb : Wqb;
  const float* __restrict__ bsel = isK ? bk : bq;
  short* __restrict__ Csel = isK ? Kb : Qb;
  const int nb = (nt & 7) * 128;

  __shared__ __align__(16) unsigned short Asm[128][72];
  __shared__ __align__(16) unsigned short Bsm[128][72];

  const int tid = threadIdx.x;
  const int wid = tid >> 6, l = tid & 63;
  const int lg = l >> 4, li = l & 15;
  const int wm = (wid >> 1) * 64, wn = (wid & 1) * 64;
  const int srow = tid >> 1, shalf = (tid & 1) * 32;

  f32x4 acc[4][4];
  #pragma unroll
  for (int i = 0; i < 4; ++i)
    #pragma unroll
    for (int j = 0; j < 4; ++j) acc[i][j] = (f32x4){0.f, 0.f, 0.f, 0.f};

  for (int kt = 0; kt < E_; kt += 64) {
    const short* ga = hsb + (size_t)(m0 + srow) * E_ + kt + shalf;
    const short* gb = Wsel + (size_t)(nb + srow) * E_ + kt + shalf;
    bf16x8 a0 = *(const bf16x8*)(ga);      bf16x8 a1 = *(const bf16x8*)(ga + 8);
    bf16x8 a2 = *(const bf16x8*)(ga + 16); bf16x8 a3 = *(const bf16x8*)(ga + 24);
    bf16x8 b0 = *(const bf16x8*)(gb);      bf16x8 b1 = *(const bf16x8*)(gb + 8);
    bf16x8 b2 = *(const bf16x8*)(gb + 16); bf16x8 b3 = *(const bf16x8*)(gb + 24);
    __syncthreads();
    *(bf16x8*)&Asm[srow][shalf + 0]  = a0; *(bf16x8*)&Asm[srow][shalf + 8]  = a1;
    *(bf16x8*)&Asm[srow][shalf + 16] = a2; *(bf16x8*)&Asm[srow][shalf + 24] = a3;
    *(bf16x8*)&Bsm[srow][shalf + 0]  = b0; *(bf16x8*)&Bsm[srow][shalf + 8]  = b1;
    *(bf16x8*)&Bsm[srow][shalf + 16] = b2; *(bf16x8*)&Bsm[srow][shalf + 24] = b3;
    __syncthreads();
    #pragma unroll
    for (int kb = 0; kb < 2; ++kb) {
      bf16x8 af[4], bfv[4];
      #pragma unroll
      for (int i = 0; i < 4; ++i)
        af[i] = *(const bf16x8*)&Asm[wm + i * 16 + li][kb * 32 + lg * 8];
      #pragma unroll
      for (int j = 0; j < 4; ++j)
        bfv[j] = *(const bf16x8*)&Bsm[wn + j * 16 + li][kb * 32 + lg * 8];
      #pragma unroll
      for (int i = 0; i < 4; ++i)
        #pragma unroll
        for (int j = 0; j < 4; ++j)
          acc[i][j] = __builtin_amdgcn_mfma_f32_16x16x32_bf16(af[i], bfv[j], acc[i][j], 0, 0, 0);
    }
  }

  #pragma unroll
  for (int j = 0; j < 4; ++j) {
    const int n = nb + wn + j * 16 + li;
    const float bv = bsel[n];
    #pragma unroll
    for (int i = 0; i < 4; ++i) {
      #pragma unroll
      for (int r = 0; r < 4; ++r) {
        const int m = m0 + wm + i * 16 + lg * 4 + r;
        Csel[(size_t)m * E_ + n] = f2bf(acc[i][j][r] + bv);
      }
    }
  }
}

// --------------------- K2a: per-head softmax denominators ------------------
__global__ __launch_bounds__(256) void zsum_kernel(
    const short* __restrict__ Qb, const short* __restrict__ Kb,
    const int* __restrict__ clen, float* __restrict__ rzinv)
{
  const int b = blockIdx.z, h = blockIdx.y;
  const int t0 = ((int)gridDim.x - 1 - (int)blockIdx.x) * 64;
  const int w = threadIdx.x >> 6, l = threadIdx.x & 63;
  const int lg = l >> 4, li = l & 15;
  const int tw = t0 + w * 16;

  const short* qrow = Qb + (size_t)(b * T_ + tw + li) * E_ + h * DH_ + lg * 8;
  const bf16x8 af0 = *(const bf16x8*)(qrow);
  const bf16x8 af1 = *(const bf16x8*)(qrow + 32);

  int lenc[4];
  #pragma unroll
  for (int r = 0; r < 4; ++r) {
    int L = clen[tw + lg * 4 + r];
    lenc[r] = L < 0 ? 0 : (L > T_ ? T_ : L);
  }
  int wmax = max(max(lenc[0], lenc[1]), max(lenc[2], lenc[3]));
  #pragma unroll
  for (int off = 32; off; off >>= 1) wmax = max(wmax, __shfl_xor(wmax, off));

  float zacc[4] = {0.f, 0.f, 0.f, 0.f};
  const short* kbase = Kb + (size_t)b * T_ * E_ + h * DH_ + lg * 8;

  for (int s0 = 0; s0 < wmax; s0 += 64) {
    f32x4 sc[4];
    #pragma unroll
    for (int n = 0; n < 4; ++n) {
      const short* krow = kbase + (size_t)(s0 + n * 16 + li) * E_;
      const bf16x8 bf0 = *(const bf16x8*)(krow);
      const bf16x8 bf1 = *(const bf16x8*)(krow + 32);
      f32x4 z4 = {0.f, 0.f, 0.f, 0.f};
      z4 = __builtin_amdgcn_mfma_f32_16x16x32_bf16(af0, bf0, z4, 0, 0, 0);
      z4 = __builtin_amdgcn_mfma_f32_16x16x32_bf16(af1, bf1, z4, 0, 0, 0);
      sc[n] = z4;
    }
    #pragma unroll
    for (int n = 0; n < 4; ++n) {
      const int s = s0 + n * 16 + li;
      #pragma unroll
      for (int r = 0; r < 4; ++r)
        if (s < lenc[r]) zacc[r] += __expf(sc[n][r] * SCALE_);
    }
  }

  #pragma unroll
  for (int r = 0; r < 4; ++r) {
    float z = zacc[r];
    #pragma unroll
    for (int off = 1; off < 16; off <<= 1) z += __shfl_xor(z, off);
    if (li == 0) {
      const int t = tw + lg * 4 + r;
      rzinv[(size_t)(b * NH_ + h) * T_ + t] =
          (lenc[r] > 0 && z > 0.f) ? 1.f / z : 0.f;
    }
  }
}

// --------------- K2b: attn_w -> gumbel -> EL (bf16 hi/lo), L ---------------
// grid (T/16, NSTRIP, B): block = 16 q-rows x 512-col s-strip.
__global__ __launch_bounds__(256) void elgen_kernel(
    const short* __restrict__ Qb, const short* __restrict__ Kb,
    const float* __restrict__ rzinv, const float* __restrict__ gum,
    const int* __restrict__ clen,
    short* __restrict__ ELh, short* __restrict__ ELl, float* __restrict__ Lws)
{
  const int b = blockIdx.z;
  const int sstart = blockIdx.y * (T_ / NSTRIP_);
  const int send = sstart + (T_ / NSTRIP_);
  const int t0 = ((int)gridDim.x - 1 - (int)blockIdx.x) * 16;
  const int tid = threadIdx.x;
  const int w = tid >> 6, l = tid & 63;
  const int lg = l >> 4, li = l & 15;

  __shared__ float awbuf[4][16][68];
  __shared__ int len_s[16];
  __shared__ int lmax_s;

  if (tid < 16) {
    int L = clen[t0 + tid];
    len_s[tid] = L < 0 ? 0 : (L > T_ ? T_ : L);
  }
  __syncthreads();
  if (tid == 0) {
    int m = 0;
    for (int i = 0; i < 16; ++i) m = max(m, len_s[i]);
    lmax_s = m;
  }

  bf16x8 af[4][2];
  const short* qrow = Qb + (size_t)(b * T_ + t0 + li) * E_ + lg * 8;
  #pragma unroll
  for (int hl = 0; hl < 4; ++hl) {
    af[hl][0] = *(const bf16x8*)(qrow + (w * 4 + hl) * DH_);
    af[hl][1] = *(const bf16x8*)(qrow + (w * 4 + hl) * DH_ + 32);
  }
  float rz[4][4];
  #pragma unroll
  for (int hl = 0; hl < 4; ++hl)
    #pragma unroll
    for (int r = 0; r < 4; ++r)
      rz[hl][r] = rzinv[(size_t)(b * NH_ + w * 4 + hl) * T_ + t0 + lg * 4 + r];
  __syncthreads();
  const int lmax = lmax_s;

  const int erow = tid >> 4;
  const int c0 = (tid & 15) * 4;
  const int elen = len_s[erow];
  float lacc = 0.f;
  const short* kbase = Kb + (size_t)b * T_ * E_ + lg * 8;
  const size_t myrow = (size_t)(b * T_ + t0 + erow);

  for (int s0 = sstart; s0 < send; s0 += 64) {
    float el[4] = {0.f, 0.f, 0.f, 0.f};
    if (s0 < lmax) {                        // block-uniform branch
      float awp[4][4];
      #pragma unroll
      for (int n = 0; n < 4; ++n)
        #pragma unroll
        for (int r = 0; r < 4; ++r) awp[n][r] = 0.f;

      #pragma unroll
      for (int hl = 0; hl < 4; ++hl) {
        f32x4 sc[4];
        #pragma unroll
        for (int n = 0; n < 4; ++n) {
          const short* krow = kbase + (size_t)(s0 + n * 16 + li) * E_ + (w * 4 + hl) * DH_;
          const bf16x8 bf0 = *(const bf16x8*)(krow);
          const bf16x8 bf1 = *(const bf16x8*)(krow + 32);
          f32x4 z4 = {0.f, 0.f, 0.f, 0.f};
          z4 = __builtin_amdgcn_mfma_f32_16x16x32_bf16(af[hl][0], bf0, z4, 0, 0, 0);
          z4 = __builtin_amdgcn_mfma_f32_16x16x32_bf16(af[hl][1], bf1, z4, 0, 0, 0);
          sc[n] = z4;
        }
        #pragma unroll
        for (int n = 0; n < 4; ++n)
          #pragma unroll
          for (int r = 0; r < 4; ++r)
            awp[n][r] += __expf(sc[n][r] * SCALE_) * rz[hl][r];
      }
      #pragma unroll
      for (int n = 0; n < 4; ++n)
        #pragma unroll
        for (int r = 0; r < 4; ++r)
          awbuf[w][lg * 4 + r][n * 16 + li] = awp[n][r];
      __syncthreads();

      #pragma unroll
      for (int j = 0; j < 4; ++j) {
        const int s = s0 + c0 + j;
        if (s < elen) {
          const float aw = awbuf[0][erow][c0 + j] + awbuf[1][erow][c0 + j] +
                           awbuf[2][erow][c0 + j] + awbuf[3][erow][c0 + j];
          const float u = gum[myrow * (size_t)T_ + s];
          const float g = -__logf(-__logf(u));
          const float e = expf((aw * (1.f / NH_) + g) * 0.5f);
          el[j] = e;
          lacc += e;
        }
      }
      __syncthreads();
    }
    // store hi/lo split (zeros where masked)
    ushort4 oh, ol;
    #pragma unroll
    for (int j = 0; j < 4; ++j) {
      const short hi = f2bf(el[j]);
      const short lo = f2bf(el[j] - bf2f(hi));
      ((unsigned short*)&oh)[j] = (unsigned short)hi;
      ((unsigned short*)&ol)[j] = (unsigned short)lo;
    }
    *(ushort4*)(ELh + myrow * (size_t)T_ + s0 + c0) = oh;
    *(ushort4*)(ELl + myrow * (size_t)T_ + s0 + c0) = ol;
  }

  #pragma unroll
  for (int off = 1; off < 16; off <<= 1) lacc += __shfl_xor(lacc, off);
  if ((tid & 15) == 0 && elen > 0)
    atomicAdd(&Lws[myrow], lacc);
}

// ----------------------- K3: output MFMA + normalize -----------------------
// out[m,e] = (sum_s (ELh+ELl)[m,s]*(Hh+Hl)[s,e]) / L[m]; 64x128 tile, BK=32.
__global__ __launch_bounds__(256) void out_mfma(
    const short* __restrict__ ELh, const short* __restrict__ ELl,
    const short* __restrict__ HTh, const short* __restrict__ HTl,
    const float* __restrict__ Lws, const int* __restrict__ clen,
    float* __restrict__ outp)
{
  const int e0 = blockIdx.x * 128;
  const int m0 = ((int)gridDim.y - 1 - (int)blockIdx.y) * 64;   // long tiles first
  const int b = m0 >> 11;                  // / T_
  const int tl0 = m0 & (T_ - 1);
  const int tid = threadIdx.x;
  const int wid = tid >> 6, l = tid & 63;
  const int lg = l >> 4, li = l & 15;

  __shared__ __align__(16) unsigned short Ah[64][40], Al[64][40];
  __shared__ __align__(16) unsigned short Bh[128][40], Bl[128][40];
  __shared__ int smax_sh;

  if (tid == 0) smax_sh = 0;
  __syncthreads();
  if (tid < 64) {
    int L = clen[tl0 + tid];
    L = L < 0 ? 0 : (L > T_ ? T_ : L);
    atomicMax(&smax_sh, L);
  }
  __syncthreads();
  const int kend = (smax_sh + 31) & ~31;

  const int arow = tid >> 2, aq = (tid & 3) * 8;
  const int brow = tid >> 1, bq8 = (tid & 1) * 16;

  f32x4 acc[8];
  #pragma unroll
  for (int j = 0; j < 8; ++j) acc[j] = (f32x4){0.f, 0.f, 0.f, 0.f};

  for (int s0 = 0; s0 < kend; s0 += 32) {
    const bf16x8 vah = *(const bf16x8*)(ELh + (size_t)(m0 + arow) * T_ + s0 + aq);
    const bf16x8 val = *(const bf16x8*)(ELl + (size_t)(m0 + arow) * T_ + s0 + aq);
    const size_t bsrc = ((size_t)(b * E_ + e0 + brow)) * T_ + s0 + bq8;
    const bf16x8 vbh0 = *(const bf16x8*)(HTh + bsrc);
    const bf16x8 vbh1 = *(const bf16x8*)(HTh + bsrc + 8);
    const bf16x8 vbl0 = *(const bf16x8*)(HTl + bsrc);
    const bf16x8 vbl1 = *(const bf16x8*)(HTl + bsrc + 8);
    __syncthreads();
    *(bf16x8*)&Ah[arow][aq] = vah;
    *(bf16x8*)&Al[arow][aq] = val;
    *(bf16x8*)&Bh[brow][bq8] = vbh0; *(bf16x8*)&Bh[brow][bq8 + 8] = vbh1;
    *(bf16x8*)&Bl[brow][bq8] = vbl0; *(bf16x8*)&Bl[brow][bq8 + 8] = vbl1;
    __syncthreads();
    const bf16x8 ah = *(const bf16x8*)&Ah[wid * 16 + li][lg * 8];
    const bf16x8 al = *(const bf16x8*)&Al[wid * 16 + li][lg * 8];
    #pragma unroll
    for (int j = 0; j < 8; ++j) {
      const bf16x8 bh = *(const bf16x8*)&Bh[j * 16 + li][lg * 8];
      const bf16x8 bl = *(const bf16x8*)&Bl[j * 16 + li][lg * 8];
      acc[j] = __builtin_amdgcn_mfma_f32_16x16x32_bf16(ah, bh, acc[j], 0, 0, 0);
      acc[j] = __builtin_amdgcn_mfma_f32_16x16x32_bf16(ah, bl, acc[j], 0, 0, 0);
      acc[j] = __builtin_amdgcn_mfma_f32_16x16x32_bf16(al, bh, acc[j], 0, 0, 0);
    }
  }

  #pragma unroll
  for (int r = 0; r < 4; ++r) {
    const int m = m0 + wid * 16 + lg * 4 + r;
    const float Lv = Lws[m];
    const float inv = (Lv > 0.f) ? 1.f / Lv : 0.f;
    #pragma unroll
    for (int j = 0; j < 8; ++j)
      outp[(size_t)m * E_ + e0 + j * 16 + li] = acc[j][r] * inv;
  }
}

// ------------------------------- launcher ----------------------------------
extern "C" void kernel_launch(void* const* d_in, const int* in_sizes, int n_in,
                              void* d_out, int out_size, void* d_ws, size_t ws_size,
                              hipStream_t stream) {
  const float* hs  = (const float*)d_in[0];
  const float* Wq  = (const float*)d_in[1];
  const float* bq  = (const float*)d_in[2];
  const float* Wk  = (const float*)d_in[3];
  const float* bk  = (const float*)d_in[4];
  const float* gum = (const float*)d_in[5];
  const int*   cl  = (const int*)d_in[6];
  float* out = (float*)d_out;

  short* hs_hi  = (short*)d_ws;
  short* hsT_hi = hs_hi  + (size_t)M_ * E_;
  short* hsT_lo = hsT_hi + (size_t)B_ * E_ * T_;
  short* Wqb    = hsT_lo + (size_t)B_ * E_ * T_;
  short* Wkb    = Wqb + (size_t)E_ * E_;
  short* Qb     = Wkb + (size_t)E_ * E_;
  short* Kb     = Qb + (size_t)M_ * E_;
  short* ELh    = Kb + (size_t)M_ * E_;
  short* ELl    = ELh + (size_t)M_ * T_;
  float* rz     = (float*)(ELl + (size_t)M_ * T_);
  float* Lw     = rz + (size_t)B_ * NH_ * T_;
  (void)ws_size; (void)in_sizes; (void)n_in; (void)out_size;

  prep_hs<<<dim3(T_ / 64, E_ / 64, B_), 256, 0, stream>>>(hs, hs_hi, hsT_hi, hsT_lo);
  cast_w<<<dim3((E_ * E_) / (256 * 4)), 256, 0, stream>>>(Wq, Wk, Wqb, Wkb);
  proj_mfma<<<dim3(16, M_ / 128), 256, 0, stream>>>(hs_hi, Wqb, Wkb, bq, bk, Qb, Kb);
  zsum_kernel<<<dim3(T_ / 64, NH_, B_), 256, 0, stream>>>(Qb, Kb, cl, rz);
  hipMemsetAsync(Lw, 0, (size_t)M_ * sizeof(float), stream);
  elgen_kernel<<<dim3(T_ / 16, NSTRIP_, B_), 256, 0, stream>>>(
      Qb, Kb, rz, gum, cl, ELh, ELl, Lw);
  out_mfma<<<dim3(E_ / 128, M_ / 64), 256, 0, stream>>>(
      ELh, ELl, hsT_hi, hsT_lo, Lw, cl, out);
}